// Round 3
// baseline (198.062 us; speedup 1.0000x reference)
//
#include <hip/hip_runtime.h>
#include <math.h>

#define D 64

// ---------------- K2: logits (16 lanes x float4 per edge, 8 edges/wave/iter) ----------------
// Also zeroes out[] and row_sum[] in its prologue (consumed only by later kernels).
__global__ __launch_bounds__(256) void k_logits(
    const int* __restrict__ sel, const float* __restrict__ hc,
    const float* __restrict__ hu, const float* __restrict__ re,
    const float* __restrict__ wsm, const float* __restrict__ bias,
    const float* __restrict__ out_w, const float* __restrict__ out_b,
    float* __restrict__ logits, int* __restrict__ seg_start,
    float* __restrict__ out, float* __restrict__ row_sum,
    int E, int BN, int Bn)
{
    const int tid = blockIdx.x * 256 + threadIdx.x;
    const int nthreads = gridDim.x * 256;

    // prologue: zero output + row sums (used by K3/K4; kernel boundary orders it)
    for (int i = tid; i < BN; i += nthreads) out[i] = 0.f;
    if (tid < Bn) row_sum[tid] = 0.f;

    const int lane = threadIdx.x & 63;
    const int g    = lane >> 4;    // edge-group within wave (0..3)
    const int d16  = lane & 15;    // lane within group; covers d = d16*4 .. d16*4+3

    // hoist constants into registers (amortized over grid-stride loop)
    const float4* wsm4 = (const float4*)wsm;
    float4 W[8];
    #pragma unroll
    for (int k = 0; k < 8; ++k) W[k] = wsm4[k * 16 + d16];
    const float4 Bv = ((const float4*)bias)[d16];
    const float4 Ow = ((const float4*)out_w)[d16];
    const float4 Ob = ((const float4*)out_b)[d16];
    const float* Wf  = (const float*)W;
    const float* Bvf = (const float*)&Bv;
    const float* Owf = (const float*)&Ow;
    const float* Obf = (const float*)&Ob;

    const float4* hc4 = (const float4*)hc;
    const float4* hu4 = (const float4*)hu;
    const float4* re4 = (const float4*)re;

    const int wave   = tid >> 6;
    const int nwaves = nthreads >> 6;
    const int octs   = (E + 7) >> 3;

    for (int q = wave; q < octs; q += nwaves) {
        const int e0 = q * 8 + g;
        const int e1 = q * 8 + 4 + g;
        const bool v0 = (e0 < E);
        const bool v1 = (e1 < E);
        const int ec0 = v0 ? e0 : (E - 1);
        const int ec1 = v1 ? e1 : (E - 1);

        // issue all index loads first
        const int4 sA0 = *(const int4*)(sel + (size_t)ec0 * 8);
        const int4 sB0 = *(const int4*)(sel + (size_t)ec0 * 8 + 4);
        const int4 sA1 = *(const int4*)(sel + (size_t)ec1 * 8);
        const int4 sB1 = *(const int4*)(sel + (size_t)ec1 * 8 + 4);

        // issue all 10 gathers (independent -> 10 VMEM in flight)
        const float4 a0  = hc4[(size_t)sB0.z * 16 + d16];
        const float4 c0  = hc4[(size_t)sB0.w * 16 + d16];
        const float4 ui0 = hu4[(size_t)sA0.y * 16 + d16];
        const float4 uj0 = hu4[(size_t)sA0.z * 16 + d16];
        const float4 r0  = re4[(size_t)sA0.w * 16 + d16];
        const float4 a1  = hc4[(size_t)sB1.z * 16 + d16];
        const float4 c1  = hc4[(size_t)sB1.w * 16 + d16];
        const float4 ui1 = hu4[(size_t)sA1.y * 16 + d16];
        const float4 uj1 = hu4[(size_t)sA1.z * 16 + d16];
        const float4 r1  = re4[(size_t)sA1.w * 16 + d16];

        float acc0 = 0.f, acc1 = 0.f;
        {
            const float* ap = (const float*)&a0;  const float* cp = (const float*)&c0;
            const float* up = (const float*)&ui0; const float* vp = (const float*)&uj0;
            const float* rp = (const float*)&r0;
            #pragma unroll
            for (int k4 = 0; k4 < 4; ++k4) {
                const float hcvi = ap[k4], hcvj = cp[k4], huvi = up[k4], huvj = vp[k4], rr = rp[k4];
                const float hcr = hcvi * rr, hur = huvi * rr;
                float f = Bvf[k4];
                f += Wf[0*4+k4] * (hcvi * hcvj);
                f += Wf[1*4+k4] * (hcr  * hcvj);
                f += Wf[2*4+k4] * (hcvi * huvj);
                f += Wf[3*4+k4] * (hcr  * huvj);
                f += Wf[4*4+k4] * (huvi * hcvj);
                f += Wf[5*4+k4] * (hur  * hcvj);
                f += Wf[6*4+k4] * (huvi * huvj);
                f += Wf[7*4+k4] * (hur  * huvj);
                acc0 += fmaxf(f, 0.f) * Owf[k4] + Obf[k4];
            }
        }
        {
            const float* ap = (const float*)&a1;  const float* cp = (const float*)&c1;
            const float* up = (const float*)&ui1; const float* vp = (const float*)&uj1;
            const float* rp = (const float*)&r1;
            #pragma unroll
            for (int k4 = 0; k4 < 4; ++k4) {
                const float hcvi = ap[k4], hcvj = cp[k4], huvi = up[k4], huvj = vp[k4], rr = rp[k4];
                const float hcr = hcvi * rr, hur = huvi * rr;
                float f = Bvf[k4];
                f += Wf[0*4+k4] * (hcvi * hcvj);
                f += Wf[1*4+k4] * (hcr  * hcvj);
                f += Wf[2*4+k4] * (hcvi * huvj);
                f += Wf[3*4+k4] * (hcr  * huvj);
                f += Wf[4*4+k4] * (huvi * hcvj);
                f += Wf[5*4+k4] * (hur  * hcvj);
                f += Wf[6*4+k4] * (huvi * huvj);
                f += Wf[7*4+k4] * (hur  * huvj);
                acc1 += fmaxf(f, 0.f) * Owf[k4] + Obf[k4];
            }
        }

        // reduce across the 16 lanes of each group
        #pragma unroll
        for (int off = 8; off > 0; off >>= 1) {
            acc0 += __shfl_xor(acc0, off, 64);
            acc1 += __shfl_xor(acc1, off, 64);
        }

        // previous-edge idx_vi via shuffles:
        //   prev(e0,g>0) = idxvi0(g-1);  prev(e0,g==0) = global load (edge q*8-1)
        //   prev(e1,g>0) = idxvi1(g-1);  prev(e1,g==0) = idxvi0(g=3)
        const int idxvi0 = sB0.x, idxvi1 = sB1.x;
        const int srcm16 = (lane >= 16) ? (lane - 16) : lane;
        const int p0w = __shfl(idxvi0, srcm16, 64);
        const int p1w = __shfl(idxvi1, srcm16, 64);
        const int p1b = __shfl(idxvi0, 48 + d16, 64);

        if (d16 == 0) {
            if (v0) {
                logits[e0] = acc0;
                int prev;
                if (e0 == 0)     prev = -1;
                else if (g == 0) prev = sel[(size_t)(e0 - 1) * 8 + 4];
                else             prev = p0w;
                if (idxvi0 != prev) seg_start[idxvi0] = e0;
            }
            if (v1) {
                logits[e1] = acc1;
                const int prev = (g == 0) ? p1b : p1w;
                if (idxvi1 != prev) seg_start[idxvi1] = e1;
            }
        }
    }
}

// ---------------- K3: edge-parallel softmax + scatter-add + row sums ----------------
// Each edge redundantly computes its segment's (max, sum) — segments are short
// (avg 1.75 edges) and contiguous, so the redundant logits reads hit L1/L2.
__global__ __launch_bounds__(256) void k_softmax_scatter(
    const int* __restrict__ sel, const float* __restrict__ logits,
    const int* __restrict__ seg_start, const float* __restrict__ na,
    const float* __restrict__ edges_y, const int* __restrict__ n_vi_seg_p,
    float* __restrict__ out, float* __restrict__ row_sum, int E, int N)
{
    const int e = blockIdx.x * 256 + threadIdx.x;
    float ta = 0.f;
    int idx = 0;
    if (e < E) {
        const int4 A = *(const int4*)(sel + (size_t)e * 8);     // idx, vi, vj, rel
        const int  s = sel[(size_t)e * 8 + 4];                  // idx_vi
        idx = A.x;
        const int nseg  = *n_vi_seg_p;
        const int start = seg_start[s];
        const int end   = (s + 1 < nseg) ? seg_start[s + 1] : E;

        const float myl  = logits[e];
        const float na_e = na[(size_t)idx * N + A.y];
        const float ye   = edges_y[e];

        float m = myl;
        for (int i = start; i < end; ++i) m = fmaxf(m, logits[i]);
        float sum = 0.f;
        for (int i = start; i < end; ++i) sum += __expf(logits[i] - m);

        ta = na_e * (__expf(myl - m) / sum) * ye;
        atomicAdd(out + (size_t)idx * N + A.z, ta);
    }

    // per-batch row-sum: edges are sorted by idx, so waves are almost always idx-uniform
    const int first = __shfl(idx, 0, 64);
    if (__all(idx == first)) {
        float v = ta;
        #pragma unroll
        for (int off = 32; off > 0; off >>= 1)
            v += __shfl_xor(v, off, 64);
        if ((threadIdx.x & 63) == 0 && v != 0.f) atomicAdd(row_sum + first, v);
    } else {
        if (ta != 0.f) atomicAdd(row_sum + idx, ta);
    }
}

// ---------------- K4: normalize rows (float4, 2D grid) ----------------
__global__ void k_norm(float4* __restrict__ out, const float* __restrict__ row_sum, int N4) {
    const int col = blockIdx.x * blockDim.x + threadIdx.x;
    const int row = blockIdx.y;
    if (col < N4) {
        const float inv = 1.f / row_sum[row];
        const size_t i = (size_t)row * N4 + col;
        float4 v = out[i];
        v.x *= inv; v.y *= inv; v.z *= inv; v.w *= inv;
        out[i] = v;
    }
}

extern "C" void kernel_launch(void* const* d_in, const int* in_sizes, int n_in,
                              void* d_out, int out_size, void* d_ws, size_t ws_size,
                              hipStream_t stream)
{
    const float* na    = (const float*)d_in[0];   // (B,N)
    const int*   sel   = (const int*)  d_in[1];   // (E,8)
    const float* ey    = (const float*)d_in[2];   // (E,)
    const float* hc    = (const float*)d_in[3];   // (n_visited, D)
    const float* hu    = (const float*)d_in[4];   // (1,N,D)
    const float* re    = (const float*)d_in[5];   // (R,D)
    const float* wsm   = (const float*)d_in[6];   // (8,D)
    const float* bias  = (const float*)d_in[7];   // (D,)
    const float* ow    = (const float*)d_in[8];   // (D,)
    const float* ob    = (const float*)d_in[9];   // (D,)
    const int* n_vi_seg_p = (const int*)d_in[10]; // scalar
    // d_in[11] = n_vj_seg (unused: idx_vj segmentation collapses to direct scatter)

    float* out = (float*)d_out;

    const int E  = in_sizes[2];
    const int N  = in_sizes[4] / D;   // hidden_uncon = N*D
    const int BN = in_sizes[0];       // B*N
    const int Bn = BN / N;

    // workspace: logits (E floats) | seg_start (E ints) | row_sum (B floats)
    float* logits    = (float*)d_ws;
    int*   seg_start = (int*)  ((char*)d_ws + (size_t)E * 4);
    float* row_sum   = (float*)((char*)d_ws + (size_t)E * 8);

    k_logits<<<2048, 256, 0, stream>>>(sel, hc, hu, re, wsm, bias, ow, ob,
                                       logits, seg_start, out, row_sum, E, BN, Bn);
    k_softmax_scatter<<<(E + 255) / 256, 256, 0, stream>>>(sel, logits, seg_start, na, ey,
                                                           n_vi_seg_p, out, row_sum, E, N);
    dim3 ngrid((N / 4 + 255) / 256, Bn);
    k_norm<<<ngrid, 256, 0, stream>>>((float4*)out, row_sum, N / 4);
}

// Round 4
// 159.973 us; speedup vs baseline: 1.2381x; 1.2381x over previous
//
#include <hip/hip_runtime.h>
#include <math.h>

#define D 64

// ---------------- K2: logits (16 lanes x float4 per edge, 8 edges/wave/iter) ----------------
// Also zeroes out[] and row_sum[] in its prologue (consumed only by later kernels),
// and writes the seg_start sentinel seg_start[nseg] = E at the last edge.
__global__ __launch_bounds__(256) void k_logits(
    const int* __restrict__ sel, const float* __restrict__ hc,
    const float* __restrict__ hu, const float* __restrict__ re,
    const float* __restrict__ wsm, const float* __restrict__ bias,
    const float* __restrict__ out_w, const float* __restrict__ out_b,
    float* __restrict__ logits, int* __restrict__ seg_start,
    float* __restrict__ out, float* __restrict__ row_sum,
    int E, int BN, int Bn)
{
    const int tid = blockIdx.x * 256 + threadIdx.x;
    const int nthreads = gridDim.x * 256;

    // prologue: zero output + row sums (used by K3/K5; kernel boundary orders it)
    for (int i = tid; i < BN; i += nthreads) out[i] = 0.f;
    if (tid < Bn) row_sum[tid] = 0.f;

    const int lane = threadIdx.x & 63;
    const int g    = lane >> 4;    // edge-group within wave (0..3)
    const int d16  = lane & 15;    // lane within group; covers d = d16*4 .. d16*4+3

    // hoist constants into registers (amortized over grid-stride loop)
    const float4* wsm4 = (const float4*)wsm;
    float4 W[8];
    #pragma unroll
    for (int k = 0; k < 8; ++k) W[k] = wsm4[k * 16 + d16];
    const float4 Bv = ((const float4*)bias)[d16];
    const float4 Ow = ((const float4*)out_w)[d16];
    const float4 Ob = ((const float4*)out_b)[d16];
    const float* Wf  = (const float*)W;
    const float* Bvf = (const float*)&Bv;
    const float* Owf = (const float*)&Ow;
    const float* Obf = (const float*)&Ob;

    const float4* hc4 = (const float4*)hc;
    const float4* hu4 = (const float4*)hu;
    const float4* re4 = (const float4*)re;

    const int wave   = tid >> 6;
    const int nwaves = nthreads >> 6;
    const int octs   = (E + 7) >> 3;

    for (int q = wave; q < octs; q += nwaves) {
        const int e0 = q * 8 + g;
        const int e1 = q * 8 + 4 + g;
        const bool v0 = (e0 < E);
        const bool v1 = (e1 < E);
        const int ec0 = v0 ? e0 : (E - 1);
        const int ec1 = v1 ? e1 : (E - 1);

        // issue all index loads first
        const int4 sA0 = *(const int4*)(sel + (size_t)ec0 * 8);
        const int4 sB0 = *(const int4*)(sel + (size_t)ec0 * 8 + 4);
        const int4 sA1 = *(const int4*)(sel + (size_t)ec1 * 8);
        const int4 sB1 = *(const int4*)(sel + (size_t)ec1 * 8 + 4);

        // issue all 10 gathers (independent -> 10 VMEM in flight)
        const float4 a0  = hc4[(size_t)sB0.z * 16 + d16];
        const float4 c0  = hc4[(size_t)sB0.w * 16 + d16];
        const float4 ui0 = hu4[(size_t)sA0.y * 16 + d16];
        const float4 uj0 = hu4[(size_t)sA0.z * 16 + d16];
        const float4 r0  = re4[(size_t)sA0.w * 16 + d16];
        const float4 a1  = hc4[(size_t)sB1.z * 16 + d16];
        const float4 c1  = hc4[(size_t)sB1.w * 16 + d16];
        const float4 ui1 = hu4[(size_t)sA1.y * 16 + d16];
        const float4 uj1 = hu4[(size_t)sA1.z * 16 + d16];
        const float4 r1  = re4[(size_t)sA1.w * 16 + d16];

        float acc0 = 0.f, acc1 = 0.f;
        {
            const float* ap = (const float*)&a0;  const float* cp = (const float*)&c0;
            const float* up = (const float*)&ui0; const float* vp = (const float*)&uj0;
            const float* rp = (const float*)&r0;
            #pragma unroll
            for (int k4 = 0; k4 < 4; ++k4) {
                const float hcvi = ap[k4], hcvj = cp[k4], huvi = up[k4], huvj = vp[k4], rr = rp[k4];
                const float hcr = hcvi * rr, hur = huvi * rr;
                float f = Bvf[k4];
                f += Wf[0*4+k4] * (hcvi * hcvj);
                f += Wf[1*4+k4] * (hcr  * hcvj);
                f += Wf[2*4+k4] * (hcvi * huvj);
                f += Wf[3*4+k4] * (hcr  * huvj);
                f += Wf[4*4+k4] * (huvi * hcvj);
                f += Wf[5*4+k4] * (hur  * hcvj);
                f += Wf[6*4+k4] * (huvi * huvj);
                f += Wf[7*4+k4] * (hur  * huvj);
                acc0 += fmaxf(f, 0.f) * Owf[k4] + Obf[k4];
            }
        }
        {
            const float* ap = (const float*)&a1;  const float* cp = (const float*)&c1;
            const float* up = (const float*)&ui1; const float* vp = (const float*)&uj1;
            const float* rp = (const float*)&r1;
            #pragma unroll
            for (int k4 = 0; k4 < 4; ++k4) {
                const float hcvi = ap[k4], hcvj = cp[k4], huvi = up[k4], huvj = vp[k4], rr = rp[k4];
                const float hcr = hcvi * rr, hur = huvi * rr;
                float f = Bvf[k4];
                f += Wf[0*4+k4] * (hcvi * hcvj);
                f += Wf[1*4+k4] * (hcr  * hcvj);
                f += Wf[2*4+k4] * (hcvi * huvj);
                f += Wf[3*4+k4] * (hcr  * huvj);
                f += Wf[4*4+k4] * (huvi * hcvj);
                f += Wf[5*4+k4] * (hur  * hcvj);
                f += Wf[6*4+k4] * (huvi * huvj);
                f += Wf[7*4+k4] * (hur  * huvj);
                acc1 += fmaxf(f, 0.f) * Owf[k4] + Obf[k4];
            }
        }

        // reduce across the 16 lanes of each group
        #pragma unroll
        for (int off = 8; off > 0; off >>= 1) {
            acc0 += __shfl_xor(acc0, off, 64);
            acc1 += __shfl_xor(acc1, off, 64);
        }

        // previous-edge idx_vi via shuffles:
        //   prev(e0,g>0) = idxvi0(g-1);  prev(e0,g==0) = global load (edge q*8-1)
        //   prev(e1,g>0) = idxvi1(g-1);  prev(e1,g==0) = idxvi0(g=3)
        const int idxvi0 = sB0.x, idxvi1 = sB1.x;
        const int srcm16 = (lane >= 16) ? (lane - 16) : lane;
        const int p0w = __shfl(idxvi0, srcm16, 64);
        const int p1w = __shfl(idxvi1, srcm16, 64);
        const int p1b = __shfl(idxvi0, 48 + d16, 64);

        if (d16 == 0) {
            if (v0) {
                logits[e0] = acc0;
                int prev;
                if (e0 == 0)     prev = -1;
                else if (g == 0) prev = sel[(size_t)(e0 - 1) * 8 + 4];
                else             prev = p0w;
                if (idxvi0 != prev) seg_start[idxvi0] = e0;
                if (e0 == E - 1) seg_start[idxvi0 + 1] = E;   // sentinel
            }
            if (v1) {
                logits[e1] = acc1;
                const int prev = (g == 0) ? p1b : p1w;
                if (idxvi1 != prev) seg_start[idxvi1] = e1;
                if (e1 == E - 1) seg_start[idxvi1 + 1] = E;   // sentinel
            }
        }
    }
}

// ---------------- K3: edge-parallel softmax + scatter-add (NO row-sum atomics) ----------------
// Each edge redundantly computes its segment's (max, sum) — segments are short
// (avg 1.75 edges) and contiguous, so the redundant logits reads hit L1/L2.
__global__ __launch_bounds__(256) void k_softmax_scatter(
    const int* __restrict__ sel, const float* __restrict__ logits,
    const int* __restrict__ seg_start, const float* __restrict__ na,
    const float* __restrict__ edges_y,
    float* __restrict__ out, int E, int N)
{
    const int e = blockIdx.x * 256 + threadIdx.x;
    if (e >= E) return;

    const int4 A = *(const int4*)(sel + (size_t)e * 8);     // idx, vi, vj, rel
    const int  s = sel[(size_t)e * 8 + 4];                  // idx_vi
    const int start = seg_start[s];
    const int end   = seg_start[s + 1];                     // sentinel makes this always valid

    const float myl  = logits[e];
    const float na_e = na[(size_t)A.x * N + A.y];
    const float ye   = edges_y[e];

    float m = myl;
    for (int i = start; i < end; ++i) m = fmaxf(m, logits[i]);
    float sum = 0.f;
    for (int i = start; i < end; ++i) sum += __expf(logits[i] - m);

    const float ta = na_e * (__expf(myl - m) / sum) * ye;
    atomicAdd(out + (size_t)A.x * N + A.z, ta);
}

// ---------------- K5: row sums of out (few blocks, LDS reduce, 64 total atomics) ----------
__global__ __launch_bounds__(256) void k_rowsum(
    const float4* __restrict__ out, float* __restrict__ row_sum, int N4)
{
    __shared__ float red[4];
    const int row = blockIdx.y;
    float s = 0.f;
    for (int i = blockIdx.x * 256 + threadIdx.x; i < N4; i += gridDim.x * 256) {
        const float4 v = out[(size_t)row * N4 + i];
        s += v.x + v.y + v.z + v.w;
    }
    #pragma unroll
    for (int off = 32; off > 0; off >>= 1)
        s += __shfl_xor(s, off, 64);
    if ((threadIdx.x & 63) == 0) red[threadIdx.x >> 6] = s;
    __syncthreads();
    if (threadIdx.x == 0)
        atomicAdd(row_sum + row, red[0] + red[1] + red[2] + red[3]);
}

// ---------------- K4: normalize rows (float4, 2D grid) ----------------
__global__ void k_norm(float4* __restrict__ out, const float* __restrict__ row_sum, int N4) {
    const int col = blockIdx.x * blockDim.x + threadIdx.x;
    const int row = blockIdx.y;
    if (col < N4) {
        const float inv = 1.f / row_sum[row];
        const size_t i = (size_t)row * N4 + col;
        float4 v = out[i];
        v.x *= inv; v.y *= inv; v.z *= inv; v.w *= inv;
        out[i] = v;
    }
}

extern "C" void kernel_launch(void* const* d_in, const int* in_sizes, int n_in,
                              void* d_out, int out_size, void* d_ws, size_t ws_size,
                              hipStream_t stream)
{
    const float* na    = (const float*)d_in[0];   // (B,N)
    const int*   sel   = (const int*)  d_in[1];   // (E,8)
    const float* ey    = (const float*)d_in[2];   // (E,)
    const float* hc    = (const float*)d_in[3];   // (n_visited, D)
    const float* hu    = (const float*)d_in[4];   // (1,N,D)
    const float* re    = (const float*)d_in[5];   // (R,D)
    const float* wsm   = (const float*)d_in[6];   // (8,D)
    const float* bias  = (const float*)d_in[7];   // (D,)
    const float* ow    = (const float*)d_in[8];   // (D,)
    const float* ob    = (const float*)d_in[9];   // (D,)
    // d_in[10] = n_vi_seg (scalar; replaced by seg_start sentinel)
    // d_in[11] = n_vj_seg (unused: idx_vj segmentation collapses to direct scatter)

    float* out = (float*)d_out;

    const int E  = in_sizes[2];
    const int N  = in_sizes[4] / D;   // hidden_uncon = N*D
    const int BN = in_sizes[0];       // B*N
    const int Bn = BN / N;

    // workspace: logits (E floats) | seg_start (E+1 ints) | row_sum (B floats, 256B-aligned)
    float* logits    = (float*)d_ws;
    int*   seg_start = (int*)  ((char*)d_ws + (size_t)E * 4);
    const size_t rs_off = (((size_t)E * 8 + 4) + 255) & ~(size_t)255;
    float* row_sum   = (float*)((char*)d_ws + rs_off);

    k_logits<<<2048, 256, 0, stream>>>(sel, hc, hu, re, wsm, bias, ow, ob,
                                       logits, seg_start, out, row_sum, E, BN, Bn);
    k_softmax_scatter<<<(E + 255) / 256, 256, 0, stream>>>(sel, logits, seg_start, na, ey,
                                                           out, E, N);
    const int N4 = N / 4;
    dim3 rgrid(16, Bn);
    k_rowsum<<<rgrid, 256, 0, stream>>>((const float4*)out, row_sum, N4);
    dim3 ngrid((N4 + 255) / 256, Bn);
    k_norm<<<ngrid, 256, 0, stream>>>((float4*)out, row_sum, N4);
}